// Round 2
// baseline (10803.283 us; speedup 1.0000x reference)
//
#include <hip/hip_runtime.h>
#include <cstdint>

#define T_DIM 2048
#define D_DIM 16
#define H_DIM 32

typedef float f32x32 __attribute__((ext_vector_type(32)));
typedef float f32x16 __attribute__((ext_vector_type(16)));

// ws float layout:
// [0,1024)     W1q   (row-major [k][j], k=0..31, j=0..31)
// [1024,1536)  W2q   ([j][d], j=0..31, d=0..15)
// [1536,1568)  b1
// [1568,1584)  b2
// [1712,1840)  actp  packed per-j float4 {1/c_s, c_s, rho_s, L}

__global__ __launch_bounds__(256) void prep_kernel(
    const float* __restrict__ W1, const float* __restrict__ b1,
    const float* __restrict__ W2, const float* __restrict__ b2,
    const float* __restrict__ c,  const float* __restrict__ rho,
    float* __restrict__ wsp)
{
    __shared__ float red[256];
    const int t = threadIdx.x;

    // s1 = max(max|W1|, 1e-8) / 7
    float m = 0.0f;
    for (int i = t; i < 1024; i += 256) m = fmaxf(m, fabsf(W1[i]));
    red[t] = m;
    __syncthreads();
    for (int s = 128; s > 0; s >>= 1) {
        if (t < s) red[t] = fmaxf(red[t], red[t + s]);
        __syncthreads();
    }
    const float s1 = fmaxf(red[0], 1e-8f) / 7.0f;
    __syncthreads();

    // s2 = max(max|W2|, 1e-8) / 7
    m = 0.0f;
    for (int i = t; i < 512; i += 256) m = fmaxf(m, fabsf(W2[i]));
    red[t] = m;
    __syncthreads();
    for (int s = 128; s > 0; s >>= 1) {
        if (t < s) red[t] = fmaxf(red[t], red[t + s]);
        __syncthreads();
    }
    const float s2 = fmaxf(red[0], 1e-8f) / 7.0f;

    // W1q = q*s + (W - q*s), each op in fp32, no contraction across statements
    for (int i = t; i < 1024; i += 256) {
        const float w = W1[i];
        const float q = fminf(fmaxf(rintf(w / s1), -7.0f), 7.0f);
        const float qs = q * s1;
        const float resid = w - qs;
        wsp[i] = qs + resid;
    }
    for (int i = t; i < 512; i += 256) {
        const float w = W2[i];
        const float q = fminf(fmaxf(rintf(w / s2), -7.0f), 7.0f);
        const float qs = q * s2;
        const float resid = w - qs;
        wsp[1024 + i] = qs + resid;
    }
    if (t < 32) wsp[1536 + t] = b1[t];
    if (t < 16) wsp[1568 + t] = b2[t];
    if (t < 32) {
        const float cs = fmaxf(c[t], 0.1f);
        const float rs = fmaxf(rho[t], 0.0f);
        wsp[1712 + 4 * t + 0] = 1.0f / cs;
        wsp[1712 + 4 * t + 1] = cs;
        wsp[1712 + 4 * t + 2] = rs;
        wsp[1712 + 4 * t + 3] = 6.0f * cs;
    }
}

// one tree pair-op: cat[32] -> h = c19(cat@W1 + b1) -> o = h@W2 + b2
// All state in ext_vector SSA values -> guaranteed VGPRs (R1 failure: pointer
// arrays demoted to scratch -> 32 GB spill traffic).
__device__ __forceinline__ f32x16 pair_op(
    const f32x32 cat,
    const float* __restrict__ W1s, const float* __restrict__ W2s,
    const float* __restrict__ b1s, const float* __restrict__ b2s,
    const float* __restrict__ actp)
{
    f32x32 acc;
#pragma unroll
    for (int j4 = 0; j4 < 8; ++j4) {
        const float4 b = *reinterpret_cast<const float4*>(b1s + 4 * j4);
        acc[4 * j4 + 0] = b.x;
        acc[4 * j4 + 1] = b.y;
        acc[4 * j4 + 2] = b.z;
        acc[4 * j4 + 3] = b.w;
    }
#pragma unroll
    for (int k = 0; k < 32; ++k) {
        const float ck = cat[k];
#pragma unroll
        for (int j4 = 0; j4 < 8; ++j4) {
            const float4 w = *reinterpret_cast<const float4*>(W1s + k * 32 + 4 * j4);
            acc[4 * j4 + 0] = fmaf(ck, w.x, acc[4 * j4 + 0]);
            acc[4 * j4 + 1] = fmaf(ck, w.y, acc[4 * j4 + 1]);
            acc[4 * j4 + 2] = fmaf(ck, w.z, acc[4 * j4 + 2]);
            acc[4 * j4 + 3] = fmaf(ck, w.w, acc[4 * j4 + 3]);
        }
    }
    // c19 activation
#pragma unroll
    for (int j = 0; j < 32; ++j) {
        const float4 p = *reinterpret_cast<const float4*>(actp + 4 * j);
        const float xv = acc[j];
        const float scaled = xv * p.x;          // x / c_s
        const float nf = floorf(scaled);
        const float tt = scaled - nf;
        const float hh = tt * (1.0f - tt);
        const int ni = (int)nf;
        const float sgn = (ni & 1) ? -1.0f : 1.0f;
        float r = p.y * (sgn * hh + p.z * (hh * hh));
        r = (xv >= p.w) ? (xv - p.w) : r;
        r = (xv <= -p.w) ? (xv + p.w) : r;
        acc[j] = r;
    }
    f32x16 o;
#pragma unroll
    for (int d4 = 0; d4 < 4; ++d4) {
        const float4 b = *reinterpret_cast<const float4*>(b2s + 4 * d4);
        o[4 * d4 + 0] = b.x;
        o[4 * d4 + 1] = b.y;
        o[4 * d4 + 2] = b.z;
        o[4 * d4 + 3] = b.w;
    }
#pragma unroll
    for (int j = 0; j < 32; ++j) {
        const float aj = acc[j];
#pragma unroll
        for (int d4 = 0; d4 < 4; ++d4) {
            const float4 w = *reinterpret_cast<const float4*>(W2s + j * 16 + 4 * d4);
            o[4 * d4 + 0] = fmaf(aj, w.x, o[4 * d4 + 0]);
            o[4 * d4 + 1] = fmaf(aj, w.y, o[4 * d4 + 1]);
            o[4 * d4 + 2] = fmaf(aj, w.z, o[4 * d4 + 2]);
            o[4 * d4 + 3] = fmaf(aj, w.w, o[4 * d4 + 3]);
        }
    }
    return o;
}

__device__ __forceinline__ f32x32 load_cat32(const float* __restrict__ src)
{
    f32x32 cat;
#pragma unroll
    for (int v = 0; v < 8; ++v) {
        const float4 f = reinterpret_cast<const float4*>(src)[v];
        cat[4 * v + 0] = f.x;
        cat[4 * v + 1] = f.y;
        cat[4 * v + 2] = f.z;
        cat[4 * v + 3] = f.w;
    }
    return cat;
}

__global__ __launch_bounds__(256, 3) void tree_kernel(
    const float* __restrict__ x, const float* __restrict__ wsp,
    float* __restrict__ out)
{
    __shared__ float W1s[1024];
    __shared__ float W2s[512];
    __shared__ float b1s[32], b2s[16];
    __shared__ float actp[128];
    __shared__ float nodes[16][512];   // feature-major: conflict-free writes

    const int t = threadIdx.x;
    const int n = blockIdx.x;

    for (int i = t; i < 1024; i += 256) W1s[i] = wsp[i];
    for (int i = t; i < 512; i += 256) W2s[i] = wsp[1024 + i];
    if (t < 32) b1s[t] = wsp[1536 + t];
    if (t < 16) b2s[t] = wsp[1568 + t];
    if (t < 128) actp[t] = wsp[1712 + t];
    __syncthreads();

    const float* __restrict__ xrow = x + (size_t)n * (T_DIM * D_DIM);

    // head: levels 0-1 fully in registers; each lane folds 4 timesteps per u
#pragma unroll 1
    for (int u = 0; u < 2; ++u) {
        const int g = u * 256 + t;                    // L1 node index (0..511)
        const float* src = xrow + (size_t)g * 64;     // 4 timesteps * 16 floats

        const f32x16 oA = pair_op(load_cat32(src),      W1s, W2s, b1s, b2s, actp);
        const f32x16 oB = pair_op(load_cat32(src + 32), W1s, W2s, b1s, b2s, actp);
        f32x32 cat1;
#pragma unroll
        for (int d = 0; d < 16; ++d) { cat1[d] = oA[d]; cat1[16 + d] = oB[d]; }
        const f32x16 nv = pair_op(cat1, W1s, W2s, b1s, b2s, actp);
#pragma unroll
        for (int d = 0; d < 16; ++d) nodes[d][g] = nv[d];
    }
    __syncthreads();

    // tail: levels with P = 256 .. 1 pairs
#pragma unroll 1
    for (int P = 256; P >= 1; P >>= 1) {
        f32x32 cat;
        const bool active = (t < P);
        if (active) {
#pragma unroll
            for (int d = 0; d < 16; ++d) {
                const float2 f = *reinterpret_cast<const float2*>(&nodes[d][2 * t]);
                cat[d]      = f.x;
                cat[16 + d] = f.y;
            }
        }
        __syncthreads();
        if (active) {
            const f32x16 nv = pair_op(cat, W1s, W2s, b1s, b2s, actp);
            if (P > 1) {
#pragma unroll
                for (int d = 0; d < 16; ++d) nodes[d][t] = nv[d];
            } else {
#pragma unroll
                for (int d = 0; d < 16; ++d) out[(size_t)n * 16 + d] = nv[d];
            }
        }
        __syncthreads();
    }
}

extern "C" void kernel_launch(void* const* d_in, const int* in_sizes, int n_in,
                              void* d_out, int out_size, void* d_ws, size_t ws_size,
                              hipStream_t stream) {
    const float* x   = (const float*)d_in[0];
    const float* W1  = (const float*)d_in[1];
    const float* b1  = (const float*)d_in[2];
    const float* W2  = (const float*)d_in[3];
    const float* b2  = (const float*)d_in[4];
    const float* c   = (const float*)d_in[5];
    const float* rho = (const float*)d_in[6];
    float* out = (float*)d_out;
    float* wsp = (float*)d_ws;

    const int N = in_sizes[0] / (T_DIM * D_DIM);   // 4096

    prep_kernel<<<1, 256, 0, stream>>>(W1, b1, W2, b2, c, rho, wsp);
    tree_kernel<<<N, 256, 0, stream>>>(x, wsp, out);
}